// Round 1
// baseline (715.163 us; speedup 1.0000x reference)
//
#include <hip/hip_runtime.h>
#include <stdint.h>

#define D_IN 2048
#define D_H  512
#define WORDS 32          // D_IN / 64
#define BM 32             // rows per block
#define CW 4              // words per k-chunk (256 k per chunk)
#define NCH (WORDS / CW)  // 8 chunks

// Pack sign bits of W, transposed: wb[w][c] bit j = (W[w*64+j][c] < 0)
// Reads are coalesced across c (columns contiguous in W's row-major layout).
__global__ __launch_bounds__(512) void pack_w_kernel(
    const float* __restrict__ W, unsigned long long* __restrict__ wb) {
  const int w = blockIdx.x;   // 0..31
  const int c = threadIdx.x;  // 0..511
  unsigned long long bits = 0ull;
#pragma unroll 16
  for (int j = 0; j < 64; ++j) {
    float v = W[(size_t)(w * 64 + j) * D_H + c];
    bits |= (unsigned long long)(v < 0.0f) << j;
  }
  wb[(size_t)w * D_H + c] = bits;  // coalesced across c
}

// Fused: binarize+pack x rows into LDS (double-buffered k-chunks), then
// XOR+popcount GEMM against packed W bits, BN epilogue.
__global__ __launch_bounds__(256, 4) void bgemm_kernel(
    const float* __restrict__ X,
    const unsigned long long* __restrict__ wb,
    const float* __restrict__ b, const float* __restrict__ beta,
    const float* __restrict__ mm, const float* __restrict__ mv,
    float* __restrict__ out) {
  __shared__ unsigned long long xs[2][BM][CW];  // 2 KB

  const int tid = threadIdx.x;
  const int wv  = tid >> 6;   // wave id 0..3
  const int l   = tid & 63;   // lane
  const size_t m0 = (size_t)blockIdx.x * BM;

  // thread's output ownership: 8 rows x 8 cols
  const int rg = tid >> 6;    // 0..3  -> rows rg*8 + i
  const int cg = tid & 63;    // 0..63 -> cols cg*8 + j

  // ---- pack one k-chunk (CW words = CW*64 k) into xs[buf] ----
  auto pack_chunk = [&](int ch, int buf) {
    const int wbase = ch * CW;
#pragma unroll 8
    for (int idx = wv; idx < BM * CW; idx += 4) {
      const int r = idx >> 2;   // CW == 4
      const int w = idx & 3;
      float v = X[(m0 + r) * D_IN + (size_t)(wbase + w) * 64 + l];
      unsigned long long bal = __ballot(v < 0.0f);  // bit l = sign of k=w*64+l
      if (l == 0) xs[buf][r][w] = bal;
    }
  };

  unsigned acc[8][8];
#pragma unroll
  for (int i = 0; i < 8; ++i)
#pragma unroll
    for (int j = 0; j < 8; ++j) acc[i][j] = 0u;

  pack_chunk(0, 0);
  __syncthreads();

  for (int ch = 0; ch < NCH; ++ch) {
    const int buf = ch & 1;
    if (ch + 1 < NCH) pack_chunk(ch + 1, buf ^ 1);  // overlaps with compute below

#pragma unroll
    for (int w = 0; w < CW; ++w) {
      const int gw = ch * CW + w;
      unsigned long long xw[8];
#pragma unroll
      for (int i = 0; i < 8; ++i) xw[i] = xs[buf][rg * 8 + i][w];  // broadcast reads

      const ulonglong4* wp =
          (const ulonglong4*)(wb + (size_t)gw * D_H + (size_t)cg * 8);
      ulonglong4 wa = wp[0];
      ulonglong4 wbv = wp[1];
      unsigned long long wl[8] = {wa.x, wa.y, wa.z, wa.w,
                                  wbv.x, wbv.y, wbv.z, wbv.w};
#pragma unroll
      for (int j = 0; j < 8; ++j)
#pragma unroll
        for (int i = 0; i < 8; ++i)
          acc[i][j] += (unsigned)__popcll(xw[i] ^ wl[j]);
    }
    __syncthreads();
  }

  // ---- epilogue: y = (K - 2*diff) + b; out = (y - mean) * rsqrt(var+eps) + beta
  float outv[8][8];
#pragma unroll
  for (int j = 0; j < 8; ++j) {
    const int c = cg * 8 + j;
    const float bj  = b[c];
    const float mmj = mm[c];
    const float bej = beta[c];
    const float inv = rsqrtf(mv[c] + 1e-3f);
#pragma unroll
    for (int i = 0; i < 8; ++i) {
      float y = (float)(D_IN - 2 * (int)acc[i][j]) + bj;
      outv[i][j] = (y - mmj) * inv + bej;
    }
  }
#pragma unroll
  for (int i = 0; i < 8; ++i) {
    const size_t r = m0 + (size_t)rg * 8 + i;
    float4 lo = make_float4(outv[i][0], outv[i][1], outv[i][2], outv[i][3]);
    float4 hi = make_float4(outv[i][4], outv[i][5], outv[i][6], outv[i][7]);
    float4* p = (float4*)(out + r * D_H + (size_t)cg * 8);
    p[0] = lo;
    p[1] = hi;
  }
}

extern "C" void kernel_launch(void* const* d_in, const int* in_sizes, int n_in,
                              void* d_out, int out_size, void* d_ws, size_t ws_size,
                              hipStream_t stream) {
  const float* X    = (const float*)d_in[0];  // [32768, 2048]
  const float* W    = (const float*)d_in[1];  // [2048, 512]
  const float* b    = (const float*)d_in[2];  // [512]
  const float* beta = (const float*)d_in[3];  // [512]
  const float* mm   = (const float*)d_in[4];  // [512]
  const float* mv   = (const float*)d_in[5];  // [512]
  float* out = (float*)d_out;                 // [32768, 512]

  unsigned long long* wbits = (unsigned long long*)d_ws;  // 32*512*8 = 128 KB

  pack_w_kernel<<<dim3(WORDS), dim3(D_H), 0, stream>>>(W, wbits);

  const int M = in_sizes[0] / D_IN;  // 32768
  bgemm_kernel<<<dim3(M / BM), dim3(256), 0, stream>>>(X, wbits, b, beta, mm, mv, out);
}

// Round 2
// 123.126 us; speedup vs baseline: 5.8084x; 5.8084x over previous
//
#include <hip/hip_runtime.h>
#include <stdint.h>

#define D_IN 2048
#define D_H  512
#define WORDS 32          // D_IN / 64
#define BM 8              // rows per block
#define CW 4              // words per k-chunk (256 k per chunk)
#define NCH (WORDS / CW)  // 8 chunks

// Pack sign bits of W, transposed, in the SAME permuted bit order the x-pack
// produces: word w (w = ch*4 + j, ch = 0..7), bit p  <->  W[ch*256 + 4p + j][c].
// (The per-word bit permutation is irrelevant to the dot product as long as
// x-pack and w-pack agree.)
__global__ __launch_bounds__(512) void pack_w_kernel(
    const float* __restrict__ W, unsigned long long* __restrict__ wb) {
  const int w = blockIdx.x;   // 0..31
  const int c = threadIdx.x;  // 0..511
  const int ch = w >> 2;
  const int j  = w & 3;
  unsigned long long bits = 0ull;
#pragma unroll 16
  for (int p = 0; p < 64; ++p) {
    float v = W[(size_t)(ch * 256 + 4 * p + j) * D_H + c];
    bits |= (unsigned long long)(v < 0.0f) << p;  // coalesced across c
  }
  wb[(size_t)w * D_H + c] = bits;
}

// Fused: binarize+pack x rows into LDS (double-buffered k-chunks, float4
// loads + ballot), then XOR+popcount GEMM against packed W bits, BN epilogue.
// Per-thread tile 4 rows x 4 cols -> ~50 VGPRs, fits the 64-VGPR /
// 8-waves-per-SIMD occupancy tier with no spill.
__global__ __launch_bounds__(256, 4) void bgemm_kernel(
    const float* __restrict__ X,
    const unsigned long long* __restrict__ wb,
    const float* __restrict__ b, const float* __restrict__ beta,
    const float* __restrict__ mm, const float* __restrict__ mv,
    float* __restrict__ out) {
  __shared__ unsigned long long xs[2][BM][CW];  // 512 B

  const int tid = threadIdx.x;
  const int wv  = tid >> 6;   // wave id 0..3
  const int l   = tid & 63;   // lane
  const size_t m0 = (size_t)blockIdx.x * BM;

  // output ownership: 4 rows x 4 cols per thread
  const int rg = tid >> 7;    // 0..1   -> rows rg*4 + i
  const int cg = tid & 127;   // 0..127 -> cols cg*4 + j

  const float4* X4 = (const float4*)X;

  // pack one k-chunk (CW words = 256 k) into xs[buf]
  // lane l loads X[row][ch*256 + 4l .. 4l+3]; ballot j -> word ch*4+j, bit l
  auto pack_chunk = [&](int ch, int buf) {
#pragma unroll
    for (int t = 0; t < 2; ++t) {
      const int r = wv + 4 * t;  // BM=8 rows, 4 waves -> 2 rows/wave
      float4 v = X4[(m0 + r) * (D_IN / 4) + (size_t)ch * 64 + l];
      unsigned long long b0 = __ballot(v.x < 0.0f);
      unsigned long long b1 = __ballot(v.y < 0.0f);
      unsigned long long b2 = __ballot(v.z < 0.0f);
      unsigned long long b3 = __ballot(v.w < 0.0f);
      if (l == 0) {
        xs[buf][r][0] = b0;
        xs[buf][r][1] = b1;
        xs[buf][r][2] = b2;
        xs[buf][r][3] = b3;
      }
    }
  };

  unsigned acc[4][4];
#pragma unroll
  for (int i = 0; i < 4; ++i)
#pragma unroll
    for (int j = 0; j < 4; ++j) acc[i][j] = 0u;

  pack_chunk(0, 0);
  __syncthreads();

  for (int ch = 0; ch < NCH; ++ch) {
    const int buf = ch & 1;
    if (ch + 1 < NCH) pack_chunk(ch + 1, buf ^ 1);  // overlaps compute below

#pragma unroll
    for (int w = 0; w < CW; ++w) {
      const int gw = ch * CW + w;
      unsigned long long xw0 = xs[buf][rg * 4 + 0][w];  // wave-broadcast reads
      unsigned long long xw1 = xs[buf][rg * 4 + 1][w];
      unsigned long long xw2 = xs[buf][rg * 4 + 2][w];
      unsigned long long xw3 = xs[buf][rg * 4 + 3][w];
      const ulonglong2* wp =
          (const ulonglong2*)(wb + (size_t)gw * D_H + (size_t)cg * 4);
      ulonglong2 wa = wp[0];
      ulonglong2 wc = wp[1];
#pragma unroll
      for (int jj = 0; jj < 4; ++jj) {
        const unsigned long long wj = (jj == 0) ? wa.x
                                    : (jj == 1) ? wa.y
                                    : (jj == 2) ? wc.x
                                                : wc.y;
        acc[0][jj] += (unsigned)__popcll(xw0 ^ wj);
        acc[1][jj] += (unsigned)__popcll(xw1 ^ wj);
        acc[2][jj] += (unsigned)__popcll(xw2 ^ wj);
        acc[3][jj] += (unsigned)__popcll(xw3 ^ wj);
      }
    }
    __syncthreads();
  }

  // epilogue: y = (K - 2*diff) + b; out = (y - mean) * rsqrt(var+eps) + beta
  const float4 bv  = ((const float4*)b)[cg];
  const float4 mmv = ((const float4*)mm)[cg];
  const float4 bev = ((const float4*)beta)[cg];
  const float4 mvv = ((const float4*)mv)[cg];
  float inv0 = rsqrtf(mvv.x + 1e-3f);
  float inv1 = rsqrtf(mvv.y + 1e-3f);
  float inv2 = rsqrtf(mvv.z + 1e-3f);
  float inv3 = rsqrtf(mvv.w + 1e-3f);

#pragma unroll
  for (int i = 0; i < 4; ++i) {
    const size_t r = m0 + (size_t)rg * 4 + i;
    float4 o;
    o.x = ((float)(D_IN - 2 * (int)acc[i][0]) + bv.x - mmv.x) * inv0 + bev.x;
    o.y = ((float)(D_IN - 2 * (int)acc[i][1]) + bv.y - mmv.y) * inv1 + bev.y;
    o.z = ((float)(D_IN - 2 * (int)acc[i][2]) + bv.z - mmv.z) * inv2 + bev.z;
    o.w = ((float)(D_IN - 2 * (int)acc[i][3]) + bv.w - mmv.w) * inv3 + bev.w;
    ((float4*)(out + r * D_H))[cg] = o;  // lanes contiguous: coalesced 1KB/row
  }
}

extern "C" void kernel_launch(void* const* d_in, const int* in_sizes, int n_in,
                              void* d_out, int out_size, void* d_ws, size_t ws_size,
                              hipStream_t stream) {
  const float* X    = (const float*)d_in[0];  // [32768, 2048]
  const float* W    = (const float*)d_in[1];  // [2048, 512]
  const float* b    = (const float*)d_in[2];  // [512]
  const float* beta = (const float*)d_in[3];  // [512]
  const float* mm   = (const float*)d_in[4];  // [512]
  const float* mv   = (const float*)d_in[5];  // [512]
  float* out = (float*)d_out;                 // [32768, 512]

  unsigned long long* wbits = (unsigned long long*)d_ws;  // 32*512*8 = 128 KB

  pack_w_kernel<<<dim3(WORDS), dim3(D_H), 0, stream>>>(W, wbits);

  const int M = in_sizes[0] / D_IN;  // 32768
  bgemm_kernel<<<dim3(M / BM), dim3(256), 0, stream>>>(X, wbits, b, beta, mm, mv, out);
}